// Round 14
// baseline (189.897 us; speedup 1.0000x reference)
//
#include <hip/hip_runtime.h>

#define N1 1000000
#define N2 131072
#define N3 16384
#define N4 2048
#define N5 256
#define C 48
#define CAP 32    // rows/segment slots; P(Binomial(1M,1/131072) >= 33) ~ 1e-6
#define CAP4 64   // f3-children per f4 row; lambda=8, P(>=65) ~ 0
#define CAP5 64   // f4-children per f5 row; lambda=8, P(>=65) ~ 0

// ---- fused setup dispatch: [zero f3][slot-sort parent2][invert p4][invert p5]
#define ZF4 ((N3 * C) / 4)               // 196,608 float4 to zero (f3 only)
#define ZBLK (ZF4 / 256)                 // 768
#define SBLK ((N1 + 255) / 256)          // 3907
#define I4BLK (N3 / 256)                 // 64
#define I5BLK (N4 / 256)                 // 8
__global__ void setup_kernel(const int* __restrict__ parent2,
                             const int* __restrict__ parent4,
                             const int* __restrict__ parent5,
                             int* __restrict__ cnt2, int* __restrict__ rowid,
                             int* __restrict__ cnt4, int* __restrict__ kid4,
                             int* __restrict__ cnt5, int* __restrict__ kid5,
                             float4* __restrict__ f3z) {
    int b = (int)blockIdx.x;
    if (b < ZBLK) {                              // zero f3
        f3z[b * 256 + threadIdx.x] = make_float4(0.f, 0.f, 0.f, 0.f);
        return;
    }
    b -= ZBLK;
    if (b < SBLK) {                              // direct-slot sort of parent2
        int i = b * 256 + threadIdx.x;
        if (i >= N1) return;
        int p = parent2[i];
        int s = atomicAdd(&cnt2[p], 1);
        if (s < CAP) rowid[p * CAP + s] = i;
        return;
    }
    b -= SBLK;
    if (b < I4BLK) {                             // invert parent4 (r3 -> r4 lists)
        int r3 = b * 256 + threadIdx.x;
        int r4 = parent4[r3];
        int s = atomicAdd(&cnt4[r4], 1);
        if (s < CAP4) kid4[r4 * CAP4 + s] = r3;
        return;
    }
    b -= I4BLK;                                  // invert parent5 (r4 -> r5 lists)
    int r4 = b * 256 + threadIdx.x;
    int r5 = parent5[r4];
    int s = atomicAdd(&cnt5[r5], 1);
    if (s < CAP5) kid5[r5 * CAP5 + s] = r4;
}

// --------------------- fused: segment-sum + row-argmax + f3 accumulation
// One 64-lane wave per segment; 5 random rows per load instruction
// (lane l = group g=l/12 x quad c4=l%12), 3 bursts = 15 rows in flight.
// rowid read: lanes 0-15 (one line, n<=16 = 98.7%); fallback lanes 16-31.
// Epilogue: 16-shfl group-reduce, 4-shfl redistribute -> ONE contiguous
// 48-lane atomicAdd into f3 + wave argmax -> tab2.
__global__ void segsum_fused_kernel(const float* __restrict__ src,
                                    const int* __restrict__ rowid,
                                    const int* __restrict__ cnt,
                                    const int* __restrict__ parent3,
                                    float* __restrict__ f3,
                                    unsigned char* __restrict__ tab2, int nseg) {
    int wid = threadIdx.x >> 6;
    int lane = threadIdx.x & 63;
    int seg = blockIdx.x * 4 + wid;
    if (seg >= nseg) return;
    int n = cnt[seg];
    if (n > CAP) n = CAP;                       // safety clamp (never hit)
    int rv = (lane < 16 && lane < n) ? rowid[seg * CAP + lane] : 0;
    if (n > 16) {                               // rare (~1.3%), wave-uniform
        if (lane >= 16 && lane < n) rv = rowid[seg * CAP + lane];
    }
    int g = lane / 12;                          // 0..4 active, 5 = lanes 60-63
    int c4 = lane - g * 12;                     // 0..11
    const bool act = (lane < 60);
    float4 acc = make_float4(0.f, 0.f, 0.f, 0.f);
    for (int k = 0; k < n; k += 15) {           // three 5-row bursts in flight
        int r0 = __shfl(rv, k + g);
        int r1 = __shfl(rv, k + 5 + g);
        int r2 = __shfl(rv, k + 10 + g);
        bool p0 = act && (k + g < n);
        bool p1 = act && (k + 5 + g < n);
        bool p2 = act && (k + 10 + g < n);
        float4 v0 = p0 ? *(const float4*)(src + (size_t)r0 * C + c4 * 4)
                       : make_float4(0.f, 0.f, 0.f, 0.f);
        float4 v1 = p1 ? *(const float4*)(src + (size_t)r1 * C + c4 * 4)
                       : make_float4(0.f, 0.f, 0.f, 0.f);
        float4 v2 = p2 ? *(const float4*)(src + (size_t)r2 * C + c4 * 4)
                       : make_float4(0.f, 0.f, 0.f, 0.f);
        acc.x += v0.x + v1.x + v2.x;
        acc.y += v0.y + v1.y + v2.y;
        acc.z += v0.z + v1.z + v2.z;
        acc.w += v0.w + v1.w + v2.w;
    }
    // reduce across the 5 row-groups (valid on lanes 0..11)
    float4 tot = acc;
#pragma unroll
    for (int gg = 1; gg < 5; ++gg) {
        int sl = c4 + 12 * gg;
        tot.x += __shfl(acc.x, sl);
        tot.y += __shfl(acc.y, sl);
        tot.z += __shfl(acc.z, sl);
        tot.w += __shfl(acc.w, sl);
    }
    // redistribute: lane l (0..47) takes comp l%4 of quad l/4
    int q = lane >> 2;
    float vx = __shfl(tot.x, q);
    float vy = __shfl(tot.y, q);
    float vz = __shfl(tot.z, q);
    float vw = __shfl(tot.w, q);
    int m = lane & 3;
    float val = (m == 0) ? vx : (m == 1) ? vy : (m == 2) ? vz : vw;
    // ONE contiguous 48-lane atomic into f3
    int p3 = parent3[seg];
    const bool ch = (lane < C);
    if (ch) atomicAdd(&f3[(size_t)p3 * C + lane], val);
    // wave argmax (first-max tie-break: smaller index)
    float bv = ch ? val : -__builtin_inff();
    int bi = ch ? lane : 0x7fffffff;
#pragma unroll
    for (int d = 32; d > 0; d >>= 1) {
        float ov = __shfl_xor(bv, d);
        int oi = __shfl_xor(bi, d);
        if (ov > bv || (ov == bv && oi < bi)) { bv = ov; bi = oi; }
    }
    if (lane == 0) tab2[seg] = (unsigned char)bi;
}

// ------------------------------------------------------- per-row argmax
__device__ __forceinline__ int argmax48(const float4* __restrict__ row) {
    float best = -__builtin_inff();
    int bi = 0;
#pragma unroll
    for (int i = 0; i < 12; ++i) {
        float4 v = row[i];
        if (v.x > best) { best = v.x; bi = 4 * i + 0; }
        if (v.y > best) { best = v.y; bi = 4 * i + 1; }
        if (v.z > best) { best = v.z; bi = 4 * i + 2; }
        if (v.w > best) { best = v.w; bi = 4 * i + 3; }
    }
    return bi;
}

// ---- tail: levels 3+4 with exclusive ownership (NO atomics, NO f4 buffer).
// Blocks 0..255: block b owns f5 row b; walks kid5 -> kid4, computes each
// f4 row in registers (tab4 + f5 partial), LDS-reduces -> f5 row.
// Blocks 256..319: tab3 argmax over f3.
__global__ void tail_kernel(const float* __restrict__ f3,
                            const int* __restrict__ cnt4, const int* __restrict__ kid4,
                            const int* __restrict__ cnt5, const int* __restrict__ kid5,
                            float* __restrict__ f5,
                            unsigned char* __restrict__ tab3,
                            unsigned char* __restrict__ tab4) {
    int b = (int)blockIdx.x;
    if (b >= N5) {                               // tab3 role
        int r = (b - N5) * 256 + threadIdx.x;
        tab3[r] = (unsigned char)argmax48((const float4*)f3 + r * 12);
        return;
    }
    __shared__ float f5part[4][C];
    int wid = threadIdx.x >> 6;
    int lane = threadIdx.x & 63;
    const bool ch = (lane < C);
    int m5 = cnt5[b];
    if (m5 > CAP5) m5 = CAP5;
    float wacc = 0.f;
    for (int j = wid; j < m5; j += 4) {
        int r4 = kid5[b * CAP5 + j];
        int m4 = cnt4[r4];
        if (m4 > CAP4) m4 = CAP4;
        float facc = 0.f;
        for (int s = 0; s < m4; ++s) {
            int r3 = kid4[r4 * CAP4 + s];
            if (ch) facc += f3[(size_t)r3 * C + lane];
        }
        // wave argmax of this complete f4 row
        float bv = ch ? facc : -__builtin_inff();
        int bi = ch ? lane : 0x7fffffff;
#pragma unroll
        for (int d = 32; d > 0; d >>= 1) {
            float ov = __shfl_xor(bv, d);
            int oi = __shfl_xor(bi, d);
            if (ov > bv || (ov == bv && oi < bi)) { bv = ov; bi = oi; }
        }
        if (lane == 0) tab4[r4] = (unsigned char)bi;
        wacc += facc;
    }
    if (ch) f5part[wid][lane] = wacc;
    __syncthreads();
    int t = threadIdx.x;
    if (t < C)
        f5[(size_t)b * C + t] = f5part[0][t] + f5part[1][t] + f5part[2][t] + f5part[3][t];
}

// --------------- final gather: tab2/3/4 lookups + LDS-cached tab5
__global__ void final_kernel(const unsigned char* __restrict__ tab2,
                             const unsigned char* __restrict__ tab3,
                             const unsigned char* __restrict__ tab4,
                             const float4* __restrict__ f5,
                             const int4* __restrict__ idx2,
                             const int4* __restrict__ idx3,
                             const int4* __restrict__ idx4,
                             const int4* __restrict__ idx5,
                             int4* __restrict__ out) {
    __shared__ unsigned char t5[N5];
    int tid = threadIdx.x;
    t5[tid] = (unsigned char)argmax48(f5 + tid * 12);   // 256 threads = 256 rows
    __syncthreads();
    const int NQ = N1 / 4;
    int t = blockIdx.x * blockDim.x + tid;
    if (t >= NQ) return;
    int4 a = idx2[t], b = idx3[t], c = idx4[t], d = idx5[t];
    out[t] = make_int4(tab2[a.x], tab2[a.y], tab2[a.z], tab2[a.w]);
    out[NQ + t] = make_int4(tab3[b.x], tab3[b.y], tab3[b.z], tab3[b.w]);
    out[2 * NQ + t] = make_int4(tab4[c.x], tab4[c.y], tab4[c.z], tab4[c.w]);
    out[3 * NQ + t] = make_int4(t5[d.x], t5[d.y], t5[d.z], t5[d.w]);
}

extern "C" void kernel_launch(void* const* d_in, const int* in_sizes, int n_in,
                              void* d_out, int out_size, void* d_ws, size_t ws_size,
                              hipStream_t stream) {
    const float* slabel  = (const float*)d_in[0];
    const int* parent2   = (const int*)d_in[1];
    const int* parent3   = (const int*)d_in[2];
    const int* parent4   = (const int*)d_in[3];
    const int* parent5   = (const int*)d_in[4];
    const int* idx2      = (const int*)d_in[5];
    const int* idx3      = (const int*)d_in[6];
    const int* idx4      = (const int*)d_in[7];
    const int* idx5      = (const int*)d_in[8];
    int* out = (int*)d_out;   // JAX argmax output dtype is int32

    // ---- workspace layout (dwords) ----
    // [f3 | cnt2 | cnt4 | cnt5 | f5 | rowid2(N2*CAP) | kid4 | kid5 | tabs(bytes)]
    float* f3 = (float*)d_ws;
    int* cnt2 = (int*)(f3 + (size_t)N3 * C);
    int* cnt4 = cnt2 + N2;
    int* cnt5 = cnt4 + N4;
    float* f5 = (float*)(cnt5 + N5);
    int* rowid2 = (int*)(f5 + (size_t)N5 * C);
    int* kid4 = rowid2 + (size_t)N2 * CAP;
    int* kid5 = kid4 + (size_t)N4 * CAP4;
    unsigned char* tab2 = (unsigned char*)(kid5 + (size_t)N5 * CAP5);
    unsigned char* tab3 = tab2 + N2;
    unsigned char* tab4 = tab3 + N3;

    // 1) zero all counters in one contiguous fast fill (533.5 KB)
    hipMemsetAsync(cnt2, 0, (size_t)(N2 + N4 + N5) * 4, stream);

    // 2) fused setup: zero f3 | slot-sort parent2 | invert parent4 | invert parent5
    setup_kernel<<<ZBLK + SBLK + I4BLK + I5BLK, 256, 0, stream>>>(
        parent2, parent4, parent5, cnt2, rowid2, cnt4, kid4, cnt5, kid5,
        (float4*)f3);

    // 3) fused: 5-rows-per-load segment-sum + argmax->tab2 + atomic f3
    segsum_fused_kernel<<<N2 / 4, 256, 0, stream>>>(
        slabel, rowid2, cnt2, parent3, f3, tab2, N2);

    // 4) tail: exclusive-ownership levels 3+4 (f5 + tab3 + tab4, no atomics)
    tail_kernel<<<N5 + N3 / 256, 256, 0, stream>>>(
        f3, cnt4, kid4, cnt5, kid5, f5, tab3, tab4);

    // 5) final: tab lookups + per-block LDS tab5
    final_kernel<<<(N1 / 4 + 255) / 256, 256, 0, stream>>>(
        tab2, tab3, tab4, (const float4*)f5,
        (const int4*)idx2, (const int4*)idx3, (const int4*)idx4, (const int4*)idx5,
        (int4*)out);
}

// Round 16
// 171.995 us; speedup vs baseline: 1.1041x; 1.1041x over previous
//
#include <hip/hip_runtime.h>

#define N1 1000000
#define N2 131072
#define N3 16384
#define N4 2048
#define N5 256
#define C 48
#define CAP 32    // rows/segment slots; P(Binomial(1M,1/131072) >= 33) ~ 1e-6

// ---- fused setup dispatch: [zero f3|f4|f5][direct-slot sort of parent2]
#define ZF4 (((N3 + N4 + N5) * C) / 4)   // 224,256 float4 to zero
#define ZBLK ((ZF4 + 255) / 256)         // 876
#define SBLK ((N1 + 255) / 256)          // 3907
__global__ void setup_kernel(const int* __restrict__ parent2,
                             int* __restrict__ cnt2, int* __restrict__ rowid,
                             float4* __restrict__ ftab) {
    int b = (int)blockIdx.x;
    if (b < ZBLK) {                              // zero f3|f4|f5
        int i = b * 256 + threadIdx.x;
        if (i < ZF4) ftab[i] = make_float4(0.f, 0.f, 0.f, 0.f);
        return;
    }
    b -= ZBLK;                                   // direct-slot sort
    int i = b * 256 + threadIdx.x;
    if (i >= N1) return;
    int p = parent2[i];
    int s = atomicAdd(&cnt2[p], 1);
    if (s < CAP) rowid[p * CAP + s] = i;
}

// --------------------- fused: segment-sum + row-argmax + f3 accumulation
// One 64-lane wave per segment; 5 random rows per load instruction
// (lane l = group g=l/12 x quad c4=l%12), 3 bursts = 15 rows in flight.
// rowid read: lanes 0-15 (one line, n<=16 = 98.7%); fallback lanes 16-31.
// Epilogue: 16-shfl group-reduce, 4-shfl redistribute -> ONE contiguous
// 48-lane atomicAdd into f3 + wave argmax -> tab2.
// NOTE: ~107us across 3 structurally different gather forms = DRAM
// random-granule wall; do not touch.
__global__ void segsum_fused_kernel(const float* __restrict__ src,
                                    const int* __restrict__ rowid,
                                    const int* __restrict__ cnt,
                                    const int* __restrict__ parent3,
                                    float* __restrict__ f3,
                                    unsigned char* __restrict__ tab2, int nseg) {
    int wid = threadIdx.x >> 6;
    int lane = threadIdx.x & 63;
    int seg = blockIdx.x * 4 + wid;
    if (seg >= nseg) return;
    int n = cnt[seg];
    if (n > CAP) n = CAP;                       // safety clamp (never hit)
    int rv = (lane < 16 && lane < n) ? rowid[seg * CAP + lane] : 0;
    if (n > 16) {                               // rare (~1.3%), wave-uniform
        if (lane >= 16 && lane < n) rv = rowid[seg * CAP + lane];
    }
    int g = lane / 12;                          // 0..4 active, 5 = lanes 60-63
    int c4 = lane - g * 12;                     // 0..11
    const bool act = (lane < 60);
    float4 acc = make_float4(0.f, 0.f, 0.f, 0.f);
    for (int k = 0; k < n; k += 15) {           // three 5-row bursts in flight
        int r0 = __shfl(rv, k + g);
        int r1 = __shfl(rv, k + 5 + g);
        int r2 = __shfl(rv, k + 10 + g);
        bool p0 = act && (k + g < n);
        bool p1 = act && (k + 5 + g < n);
        bool p2 = act && (k + 10 + g < n);
        float4 v0 = p0 ? *(const float4*)(src + (size_t)r0 * C + c4 * 4)
                       : make_float4(0.f, 0.f, 0.f, 0.f);
        float4 v1 = p1 ? *(const float4*)(src + (size_t)r1 * C + c4 * 4)
                       : make_float4(0.f, 0.f, 0.f, 0.f);
        float4 v2 = p2 ? *(const float4*)(src + (size_t)r2 * C + c4 * 4)
                       : make_float4(0.f, 0.f, 0.f, 0.f);
        acc.x += v0.x + v1.x + v2.x;
        acc.y += v0.y + v1.y + v2.y;
        acc.z += v0.z + v1.z + v2.z;
        acc.w += v0.w + v1.w + v2.w;
    }
    // reduce across the 5 row-groups (valid on lanes 0..11)
    float4 tot = acc;
#pragma unroll
    for (int gg = 1; gg < 5; ++gg) {
        int sl = c4 + 12 * gg;
        tot.x += __shfl(acc.x, sl);
        tot.y += __shfl(acc.y, sl);
        tot.z += __shfl(acc.z, sl);
        tot.w += __shfl(acc.w, sl);
    }
    // redistribute: lane l (0..47) takes comp l%4 of quad l/4
    int q = lane >> 2;
    float vx = __shfl(tot.x, q);
    float vy = __shfl(tot.y, q);
    float vz = __shfl(tot.z, q);
    float vw = __shfl(tot.w, q);
    int m = lane & 3;
    float val = (m == 0) ? vx : (m == 1) ? vy : (m == 2) ? vz : vw;
    // ONE contiguous 48-lane atomic into f3
    int p3 = parent3[seg];
    const bool ch = (lane < C);
    if (ch) atomicAdd(&f3[(size_t)p3 * C + lane], val);
    // wave argmax (first-max tie-break: smaller index)
    float bv = ch ? val : -__builtin_inff();
    int bi = ch ? lane : 0x7fffffff;
#pragma unroll
    for (int d = 32; d > 0; d >>= 1) {
        float ov = __shfl_xor(bv, d);
        int oi = __shfl_xor(bi, d);
        if (ov > bv || (ov == bv && oi < bi)) { bv = ov; bi = oi; }
    }
    if (lane == 0) tab2[seg] = (unsigned char)bi;
}

// ------------------------------------------------------- per-row argmax
__device__ __forceinline__ int argmax48(const float4* __restrict__ row) {
    float best = -__builtin_inff();
    int bi = 0;
#pragma unroll
    for (int i = 0; i < 12; ++i) {
        float4 v = row[i];
        if (v.x > best) { best = v.x; bi = 4 * i + 0; }
        if (v.y > best) { best = v.y; bi = 4 * i + 1; }
        if (v.z > best) { best = v.z; bi = 4 * i + 2; }
        if (v.w > best) { best = v.w; bi = 4 * i + 3; }
    }
    return bi;
}

// ---- level34: ONE dispatch for levels 3+4 via composed parents + tab3.
// blocks [0,3072): element e of f3 -> atomicAdd f4[parent4[r]] AND
// f5[parent5[parent4[r]]] (f5 independent of f4 completion).
// blocks [3072,3136): tab3 argmax (f3 complete since segsum).
__global__ void level34_kernel(const float* __restrict__ f3,
                               const int* __restrict__ parent4,
                               const int* __restrict__ parent5,
                               float* __restrict__ f4,
                               float* __restrict__ f5,
                               unsigned char* __restrict__ tab3) {
    int b = (int)blockIdx.x;
    if (b < 3072) {
        int e = b * 256 + threadIdx.x;       // < N3*C = 786,432
        unsigned r = (unsigned)e / C;
        unsigned c = (unsigned)e - r * C;
        float v = f3[e];
        int r4 = parent4[r];
        atomicAdd(&f4[(size_t)r4 * C + c], v);
        int r5 = parent5[r4];
        atomicAdd(&f5[(size_t)r5 * C + c], v);
    } else {
        int r = (b - 3072) * 256 + threadIdx.x;   // < N3
        tab3[r] = (unsigned char)argmax48((const float4*)f3 + r * 12);
    }
}

// --------------- final: LDS t4[2048]+t5[256] preamble, grid-stride queries
__global__ void final_kernel(const unsigned char* __restrict__ tab2,
                             const unsigned char* __restrict__ tab3,
                             const float4* __restrict__ f4,
                             const float4* __restrict__ f5,
                             const int4* __restrict__ idx2,
                             const int4* __restrict__ idx3,
                             const int4* __restrict__ idx4,
                             const int4* __restrict__ idx5,
                             int4* __restrict__ out) {
    __shared__ unsigned char t4[N4];
    __shared__ unsigned char t5[N5];
    for (int r = threadIdx.x; r < N4; r += 256)
        t4[r] = (unsigned char)argmax48(f4 + r * 12);
    t5[threadIdx.x] = (unsigned char)argmax48(f5 + threadIdx.x * 12);
    __syncthreads();
    const int NQ = N1 / 4;
    for (int t = blockIdx.x * 256 + threadIdx.x; t < NQ; t += gridDim.x * 256) {
        int4 a = idx2[t], b = idx3[t], c = idx4[t], d = idx5[t];
        out[t]          = make_int4(tab2[a.x], tab2[a.y], tab2[a.z], tab2[a.w]);
        out[NQ + t]     = make_int4(tab3[b.x], tab3[b.y], tab3[b.z], tab3[b.w]);
        out[2 * NQ + t] = make_int4(t4[c.x], t4[c.y], t4[c.z], t4[c.w]);
        out[3 * NQ + t] = make_int4(t5[d.x], t5[d.y], t5[d.z], t5[d.w]);
    }
}

extern "C" void kernel_launch(void* const* d_in, const int* in_sizes, int n_in,
                              void* d_out, int out_size, void* d_ws, size_t ws_size,
                              hipStream_t stream) {
    const float* slabel  = (const float*)d_in[0];
    const int* parent2   = (const int*)d_in[1];
    const int* parent3   = (const int*)d_in[2];
    const int* parent4   = (const int*)d_in[3];
    const int* parent5   = (const int*)d_in[4];
    const int* idx2      = (const int*)d_in[5];
    const int* idx3      = (const int*)d_in[6];
    const int* idx4      = (const int*)d_in[7];
    const int* idx5      = (const int*)d_in[8];
    int* out = (int*)d_out;   // JAX argmax output dtype is int32

    // ---- workspace layout (dwords) ----
    // [f3 | f4 | f5 | cnt2 | rowid2(N2*CAP) | tab2|tab3 (bytes)]
    float* f3 = (float*)d_ws;
    float* f4 = f3 + (size_t)N3 * C;
    float* f5 = f4 + (size_t)N4 * C;
    int* cnt2 = (int*)(f5 + (size_t)N5 * C);
    int* rowid2 = cnt2 + N2;
    unsigned char* tab2 = (unsigned char*)(rowid2 + (size_t)N2 * CAP);
    unsigned char* tab3 = tab2 + N2;

    // 1) zero cnt2 via fast fill (512 KB)
    hipMemsetAsync(cnt2, 0, (size_t)N2 * 4, stream);

    // 2) fused setup: zero f3|f4|f5 (876 blocks) + direct-slot sort (3907)
    setup_kernel<<<ZBLK + SBLK, 256, 0, stream>>>(
        parent2, cnt2, rowid2, (float4*)d_ws);

    // 3) fused: 5-rows-per-load segment-sum + argmax->tab2 + atomic f3
    segsum_fused_kernel<<<N2 / 4, 256, 0, stream>>>(
        slabel, rowid2, cnt2, parent3, f3, tab2, N2);

    // 4) levels 3+4 in one dispatch (composed-parent atomics) + tab3
    level34_kernel<<<3072 + 64, 256, 0, stream>>>(
        f3, parent4, parent5, f4, f5, tab3);

    // 5) final: LDS t4+t5 preamble + tab lookups
    final_kernel<<<256, 256, 0, stream>>>(
        tab2, tab3, (const float4*)f4, (const float4*)f5,
        (const int4*)idx2, (const int4*)idx3, (const int4*)idx4, (const int4*)idx5,
        (int4*)out);
}

// Round 17
// 165.351 us; speedup vs baseline: 1.1484x; 1.0402x over previous
//
#include <hip/hip_runtime.h>

#define N1 1000000
#define N2 131072
#define N3 16384
#define N4 2048
#define N5 256
#define C 48
#define CAP 32    // rows/segment slots; P(Binomial(1M,1/131072) >= 33) ~ 1e-6

// ---- fused setup dispatch: [zero f3|f4|f5][direct-slot sort, int4 reads]
#define ZF4 (((N3 + N4 + N5) * C) / 4)   // 224,256 float4 to zero
#define ZBLK ((ZF4 + 255) / 256)         // 876
#define SBLK ((N1 / 4 + 255) / 256)      // 977 (int4-vectorized)
__global__ void setup_kernel(const int4* __restrict__ parent2,
                             int* __restrict__ cnt2, int* __restrict__ rowid,
                             float4* __restrict__ ftab) {
    int b = (int)blockIdx.x;
    if (b < ZBLK) {                              // zero f3|f4|f5
        int i = b * 256 + threadIdx.x;
        if (i < ZF4) ftab[i] = make_float4(0.f, 0.f, 0.f, 0.f);
        return;
    }
    b -= ZBLK;                                   // direct-slot sort, 4 rows/thread
    int i = b * 256 + threadIdx.x;
    if (i >= N1 / 4) return;
    int4 p = parent2[i];
    int r = 4 * i, s;
    s = atomicAdd(&cnt2[p.x], 1); if (s < CAP) rowid[p.x * CAP + s] = r;
    s = atomicAdd(&cnt2[p.y], 1); if (s < CAP) rowid[p.y * CAP + s] = r + 1;
    s = atomicAdd(&cnt2[p.z], 1); if (s < CAP) rowid[p.z * CAP + s] = r + 2;
    s = atomicAdd(&cnt2[p.w], 1); if (s < CAP) rowid[p.w * CAP + s] = r + 3;
}

// --------------------- fused: segment-sum + row-argmax + f3 accumulation
// One 64-lane wave per segment; 5 random rows per load instruction
// (lane l = group g=l/12 x quad c4=l%12), 3 bursts = 15 rows in flight.
// rowid read: lanes 0-15 (one line, n<=16 = 98.7%); fallback lanes 16-31.
// Epilogue: 16-shfl group-reduce, 4-shfl redistribute -> ONE contiguous
// 48-lane atomicAdd into f3 + wave argmax -> tab2.
// NOTE: ~107us across 3 structurally different gather forms = DRAM
// random-granule wall; do not touch.
__global__ void segsum_fused_kernel(const float* __restrict__ src,
                                    const int* __restrict__ rowid,
                                    const int* __restrict__ cnt,
                                    const int* __restrict__ parent3,
                                    float* __restrict__ f3,
                                    unsigned char* __restrict__ tab2, int nseg) {
    int wid = threadIdx.x >> 6;
    int lane = threadIdx.x & 63;
    int seg = blockIdx.x * 4 + wid;
    if (seg >= nseg) return;
    int n = cnt[seg];
    if (n > CAP) n = CAP;                       // safety clamp (never hit)
    int rv = (lane < 16 && lane < n) ? rowid[seg * CAP + lane] : 0;
    if (n > 16) {                               // rare (~1.3%), wave-uniform
        if (lane >= 16 && lane < n) rv = rowid[seg * CAP + lane];
    }
    int g = lane / 12;                          // 0..4 active, 5 = lanes 60-63
    int c4 = lane - g * 12;                     // 0..11
    const bool act = (lane < 60);
    float4 acc = make_float4(0.f, 0.f, 0.f, 0.f);
    for (int k = 0; k < n; k += 15) {           // three 5-row bursts in flight
        int r0 = __shfl(rv, k + g);
        int r1 = __shfl(rv, k + 5 + g);
        int r2 = __shfl(rv, k + 10 + g);
        bool p0 = act && (k + g < n);
        bool p1 = act && (k + 5 + g < n);
        bool p2 = act && (k + 10 + g < n);
        float4 v0 = p0 ? *(const float4*)(src + (size_t)r0 * C + c4 * 4)
                       : make_float4(0.f, 0.f, 0.f, 0.f);
        float4 v1 = p1 ? *(const float4*)(src + (size_t)r1 * C + c4 * 4)
                       : make_float4(0.f, 0.f, 0.f, 0.f);
        float4 v2 = p2 ? *(const float4*)(src + (size_t)r2 * C + c4 * 4)
                       : make_float4(0.f, 0.f, 0.f, 0.f);
        acc.x += v0.x + v1.x + v2.x;
        acc.y += v0.y + v1.y + v2.y;
        acc.z += v0.z + v1.z + v2.z;
        acc.w += v0.w + v1.w + v2.w;
    }
    // reduce across the 5 row-groups (valid on lanes 0..11)
    float4 tot = acc;
#pragma unroll
    for (int gg = 1; gg < 5; ++gg) {
        int sl = c4 + 12 * gg;
        tot.x += __shfl(acc.x, sl);
        tot.y += __shfl(acc.y, sl);
        tot.z += __shfl(acc.z, sl);
        tot.w += __shfl(acc.w, sl);
    }
    // redistribute: lane l (0..47) takes comp l%4 of quad l/4
    int q = lane >> 2;
    float vx = __shfl(tot.x, q);
    float vy = __shfl(tot.y, q);
    float vz = __shfl(tot.z, q);
    float vw = __shfl(tot.w, q);
    int m = lane & 3;
    float val = (m == 0) ? vx : (m == 1) ? vy : (m == 2) ? vz : vw;
    // ONE contiguous 48-lane atomic into f3
    int p3 = parent3[seg];
    const bool ch = (lane < C);
    if (ch) atomicAdd(&f3[(size_t)p3 * C + lane], val);
    // wave argmax (first-max tie-break: smaller index)
    float bv = ch ? val : -__builtin_inff();
    int bi = ch ? lane : 0x7fffffff;
#pragma unroll
    for (int d = 32; d > 0; d >>= 1) {
        float ov = __shfl_xor(bv, d);
        int oi = __shfl_xor(bi, d);
        if (ov > bv || (ov == bv && oi < bi)) { bv = ov; bi = oi; }
    }
    if (lane == 0) tab2[seg] = (unsigned char)bi;
}

// ------------------------------------------------------- per-row argmax
__device__ __forceinline__ int argmax48(const float4* __restrict__ row) {
    float best = -__builtin_inff();
    int bi = 0;
#pragma unroll
    for (int i = 0; i < 12; ++i) {
        float4 v = row[i];
        if (v.x > best) { best = v.x; bi = 4 * i + 0; }
        if (v.y > best) { best = v.y; bi = 4 * i + 1; }
        if (v.z > best) { best = v.z; bi = 4 * i + 2; }
        if (v.w > best) { best = v.w; bi = 4 * i + 3; }
    }
    return bi;
}

// ----------- fused level kernel: atomic scatter (blocks < nblkA) + row argmax
__global__ void level_kernel(const float* __restrict__ fsrc,
                             const int* __restrict__ parent,
                             float* __restrict__ fdst,
                             unsigned char* __restrict__ tabsrc,
                             int nrows, int nblkA) {
    if ((int)blockIdx.x < nblkA) {
        int e = blockIdx.x * 256 + threadIdx.x;
        if (e < nrows * C) {
            unsigned r = (unsigned)e / C;
            unsigned c = (unsigned)e - r * C;
            atomicAdd(&fdst[(unsigned)parent[r] * C + c], fsrc[e]);
        }
    } else {
        int r = (blockIdx.x - nblkA) * 256 + threadIdx.x;
        if (r < nrows) tabsrc[r] = (unsigned char)argmax48((const float4*)fsrc + r * 12);
    }
}

// --------------- final gather: tab2/3/4 lookups + LDS-cached tab5
__global__ void final_kernel(const unsigned char* __restrict__ tab2,
                             const unsigned char* __restrict__ tab3,
                             const unsigned char* __restrict__ tab4,
                             const float4* __restrict__ f5,
                             const int4* __restrict__ idx2,
                             const int4* __restrict__ idx3,
                             const int4* __restrict__ idx4,
                             const int4* __restrict__ idx5,
                             int4* __restrict__ out) {
    __shared__ unsigned char t5[N5];
    int tid = threadIdx.x;
    t5[tid] = (unsigned char)argmax48(f5 + tid * 12);   // 256 threads = 256 rows
    __syncthreads();
    const int NQ = N1 / 4;
    int t = blockIdx.x * blockDim.x + tid;
    if (t >= NQ) return;
    int4 a = idx2[t], b = idx3[t], c = idx4[t], d = idx5[t];
    out[t] = make_int4(tab2[a.x], tab2[a.y], tab2[a.z], tab2[a.w]);
    out[NQ + t] = make_int4(tab3[b.x], tab3[b.y], tab3[b.z], tab3[b.w]);
    out[2 * NQ + t] = make_int4(tab4[c.x], tab4[c.y], tab4[c.z], tab4[c.w]);
    out[3 * NQ + t] = make_int4(t5[d.x], t5[d.y], t5[d.z], t5[d.w]);
}

extern "C" void kernel_launch(void* const* d_in, const int* in_sizes, int n_in,
                              void* d_out, int out_size, void* d_ws, size_t ws_size,
                              hipStream_t stream) {
    const float* slabel  = (const float*)d_in[0];
    const int* parent2   = (const int*)d_in[1];
    const int* parent3   = (const int*)d_in[2];
    const int* parent4   = (const int*)d_in[3];
    const int* parent5   = (const int*)d_in[4];
    const int* idx2      = (const int*)d_in[5];
    const int* idx3      = (const int*)d_in[6];
    const int* idx4      = (const int*)d_in[7];
    const int* idx5      = (const int*)d_in[8];
    int* out = (int*)d_out;   // JAX argmax output dtype is int32

    // ---- workspace layout (dwords) ----
    // [f3 | f4 | f5 | cnt2 | rowid2(N2*CAP) | tab2|tab3|tab4 (bytes)]
    float* f3 = (float*)d_ws;
    float* f4 = f3 + (size_t)N3 * C;
    float* f5 = f4 + (size_t)N4 * C;
    int* cnt2 = (int*)(f5 + (size_t)N5 * C);
    int* rowid2 = cnt2 + N2;
    unsigned char* tab2 = (unsigned char*)(rowid2 + (size_t)N2 * CAP);
    unsigned char* tab3 = tab2 + N2;
    unsigned char* tab4 = tab3 + N3;

    // 1) zero cnt2 via fast fill (512 KB)
    hipMemsetAsync(cnt2, 0, (size_t)N2 * 4, stream);

    // 2) fused setup: zero f3|f4|f5 (876 blocks) + int4 slot-sort (977 blocks)
    setup_kernel<<<ZBLK + SBLK, 256, 0, stream>>>(
        (const int4*)parent2, cnt2, rowid2, (float4*)d_ws);

    // 3) fused: 5-rows-per-load segment-sum + argmax->tab2 + atomic f3
    segsum_fused_kernel<<<N2 / 4, 256, 0, stream>>>(
        slabel, rowid2, cnt2, parent3, f3, tab2, N2);

    // 4) level 3: f3->f4 atomics (3072 blocks) + tab3 argmax (64 blocks)
    level_kernel<<<3072 + 64, 256, 0, stream>>>(f3, parent4, f4, tab3, N3, 3072);

    // 5) level 4: f4->f5 atomics (384 blocks) + tab4 argmax (8 blocks)
    level_kernel<<<384 + 8, 256, 0, stream>>>(f4, parent5, f5, tab4, N4, 384);

    // 6) final: tab lookups + per-block LDS tab5
    final_kernel<<<(N1 / 4 + 255) / 256, 256, 0, stream>>>(
        tab2, tab3, tab4, (const float4*)f5,
        (const int4*)idx2, (const int4*)idx3, (const int4*)idx4, (const int4*)idx5,
        (int4*)out);
}